// Round 3
// baseline (192.052 us; speedup 1.0000x reference)
//
#include <hip/hip_runtime.h>
#include <hip/hip_cooperative_groups.h>
#include <math.h>

namespace cg = cooperative_groups;

#define BB   256   // batch
#define OBS  256
#define HH   1024
#define AA   18

// clang-native packed f16: + -> v_pk_add_f16, elementwise_max -> v_pk_max_f16
typedef _Float16 h2 __attribute__((ext_vector_type(2)));
typedef _Float16 f16x8 __attribute__((ext_vector_type(8)));
typedef float f32x4 __attribute__((ext_vector_type(4)));

static __device__ __forceinline__ h2 u2h(unsigned int u) {
  return __builtin_bit_cast(h2, u);
}
static __device__ __forceinline__ unsigned int h2u(h2 v) {
  return __builtin_bit_cast(unsigned int, v);
}
// v_cvt_pkrtz_f16_f32: two f32 -> packed f16 dword (builtin returns __fp16x2)
static __device__ __forceinline__ unsigned int pkrtz(float a, float b) {
  return __builtin_bit_cast(unsigned int, __builtin_amdgcn_cvt_pkrtz(a, b));
}

static constexpr int PITCH = 514;   // W-tile LDS pitch (conflict-free b64)

// ---------------------------------------------------------------------------
// mmplus unit: one og (8 o-rows), TWO bg units (bg0, bg0+1) with a single
// W-tile stage (same og => same W rows). wtile and red are separate LDS
// regions so no restage between the two bg passes.
// ---------------------------------------------------------------------------
template <bool IS_MAX>
static __device__ __forceinline__ void mmplus_og(
    const unsigned int* __restrict__ hpk,   // [H/2][B] dwords (i-pair, b)
    const float* __restrict__ Wf,           // [H][H] f32 (o, i)
    unsigned int* __restrict__ opk,         // [H/2][B]
    unsigned int* wtile, unsigned int* red, int og, int bg0) {
  const int t    = threadIdx.x;
  const int lane = t & 63;
  const int og2  = lane >> 4;      // o-pair group 0..3
  const int bq   = lane & 15;      // b-quad 0..15
  const int s    = __builtin_amdgcn_readfirstlane(t >> 6);  // i-split 0..15

  // ---- stage W tile once: 8 rows (two waves per row), f32 -> pk f16 ----
  {
    const int o_l = t >> 7;        // 0..7
    const int c   = t & 127;
    const float4* src = (const float4*)(Wf + (size_t)(og * 8 + o_l) * HH);
    unsigned int* dst = &wtile[o_l * PITCH];
#pragma unroll
    for (int k = 0; k < 2; ++k) {
      const float4 v = src[c + 128 * k];
      *(uint2*)&dst[(c + 128 * k) * 2] =
          make_uint2(pkrtz(v.x, v.y), pkrtz(v.z, v.w));
    }
  }
  __syncthreads();

  const _Float16 INIT = (_Float16)(IS_MAX ? -65504.f : 65504.f);

#pragma unroll 1
  for (int u = 0; u < 2; ++u) {
    const int bg = bg0 + u;
    const unsigned int* __restrict__ hp =
        hpk + (size_t)(s * 32) * BB + bg * 64 + bq * 4;

    h2 acc[2][4];
#pragma unroll
    for (int j = 0; j < 2; ++j)
#pragma unroll
      for (int bb = 0; bb < 4; ++bb) acc[j][bb] = (h2){INIT, INIT};

#define LDH(p) (*(const uint4*)(hp + (size_t)(p) * BB))
    uint4 c0 = LDH(0);
    uint4 c1 = LDH(1);
#pragma unroll
    for (int it = 0; it < 16; ++it) {
      uint4 n0, n1;
      if (it < 15) {                    // compile-time after full unroll
        n0 = LDH(2 * it + 2);
        n1 = LDH(2 * it + 3);
      }
      const int p = it * 2;
      const h2 h0v[4] = {u2h(c0.x), u2h(c0.y), u2h(c0.z), u2h(c0.w)};
      const h2 h1v[4] = {u2h(c1.x), u2h(c1.y), u2h(c1.z), u2h(c1.w)};
#pragma unroll
      for (int j = 0; j < 2; ++j) {
        const uint2 wj =
            *(const uint2*)&wtile[(og2 * 2 + j) * PITCH + s * 32 + p];
        const h2 wa = u2h(wj.x);
        const h2 wb = u2h(wj.y);
#pragma unroll
        for (int bb = 0; bb < 4; ++bb) {
          if (IS_MAX) {
            acc[j][bb] = __builtin_elementwise_max(acc[j][bb], wa + h0v[bb]);
            acc[j][bb] = __builtin_elementwise_max(acc[j][bb], wb + h1v[bb]);
          } else {
            acc[j][bb] = __builtin_elementwise_min(acc[j][bb], wa + h0v[bb]);
            acc[j][bb] = __builtin_elementwise_min(acc[j][bb], wb + h1v[bb]);
          }
        }
      }
      if (it < 15) { c0 = n0; c1 = n1; }
    }
#undef LDH

    // fold even/odd i-partials -> scalar f16 per (o,b); pack o-pair
    unsigned int opack[4];
#pragma unroll
    for (int bb = 0; bb < 4; ++bb) {
      const h2 ae = acc[0][bb], ao = acc[1][bb];
      const _Float16 me = IS_MAX ? (ae.x > ae.y ? ae.x : ae.y)
                                 : (ae.x < ae.y ? ae.x : ae.y);
      const _Float16 mo = IS_MAX ? (ao.x > ao.y ? ao.x : ao.y)
                                 : (ao.x < ao.y ? ao.x : ao.y);
      opack[bb] = h2u((h2){me, mo});
    }

#pragma unroll
    for (int bb = 0; bb < 4; ++bb)
      red[s * 256 + og2 * 64 + bq * 4 + bb] = opack[bb];
    __syncthreads();

    if (t < 256) {
      const int op = t >> 6;   // o-pair 0..3
      const int bl = t & 63;
      h2 m = u2h(red[op * 64 + bl]);
#pragma unroll
      for (int ks = 1; ks < 16; ++ks) {
        const h2 v = u2h(red[ks * 256 + op * 64 + bl]);
        m = IS_MAX ? __builtin_elementwise_max(m, v)
                   : __builtin_elementwise_min(m, v);
      }
      opk[(size_t)(og * 4 + op) * BB + bg * 64 + bl] = h2u(m);
    }
    __syncthreads();   // protect red[] before next bg pass rewrites it
  }
}

// ---------------------------------------------------------------------------
// Fused cooperative kernel: fc_in -> gridsync -> max-plus -> gridsync ->
// min-plus -> gridsync -> fc_out. 256 blocks x 1024 thr = 1 block/CU
// (co-resident; cooperative launch). Removes 3 inter-kernel launch gaps.
// ---------------------------------------------------------------------------
__global__ __launch_bounds__(1024) void fused_kernel(
    const float* __restrict__ x, const float* __restrict__ Wi,
    const float* __restrict__ bi, const float* __restrict__ Wmax,
    const float* __restrict__ Wmin, const float* __restrict__ Wo,
    const float* __restrict__ bo, float* __restrict__ q,
    unsigned int* __restrict__ h1pk, unsigned int* __restrict__ h2pk,
    unsigned int* __restrict__ h3pk) {
  __shared__ __align__(16) unsigned int wtile[8 * PITCH];   // 16.4 KB
  __shared__ __align__(16) unsigned int red[16 * 256];      // 16.0 KB

  cg::grid_group grid = cg::this_grid();
  const int t    = threadIdx.x;
  const int lane = t & 63;
  const int wv   = t >> 6;           // 0..15
  const int bid  = blockIdx.x;       // 0..255

  // ========== phase 1: fc_in (MFMA 16x16x32_f16, no LDS) ==========
  // 1024 o/b tiles over 4 waves/block (1 per SIMD). wid = bid*4 + wv.
  if (wv < 4) {
    const int wid = bid * 4 + wv;    // 0..1023
    const int ot  = wid >> 4;        // 0..63  (16 o rows)
    const int bt  = wid & 15;        // 0..15  (16 b cols)
    const int r   = lane & 15;
    const int g   = lane >> 4;       // 0..3

    const float* wrow = Wi + (size_t)(ot * 16 + r) * OBS + g * 8;
    const float* xrow = x  + (size_t)(bt * 16 + r) * OBS + g * 8;

    f32x4 acc = {0.f, 0.f, 0.f, 0.f};
#pragma unroll
    for (int ks = 0; ks < 8; ++ks) {
      const float4 wa = *(const float4*)(wrow + ks * 32);
      const float4 wb = *(const float4*)(wrow + ks * 32 + 4);
      const float4 xa = *(const float4*)(xrow + ks * 32);
      const float4 xb = *(const float4*)(xrow + ks * 32 + 4);
      const uint4 au = make_uint4(pkrtz(wa.x, wa.y), pkrtz(wa.z, wa.w),
                                  pkrtz(wb.x, wb.y), pkrtz(wb.z, wb.w));
      const uint4 bu = make_uint4(pkrtz(xa.x, xa.y), pkrtz(xa.z, xa.w),
                                  pkrtz(xb.x, xb.y), pkrtz(xb.z, xb.w));
      acc = __builtin_amdgcn_mfma_f32_16x16x32_f16(
          __builtin_bit_cast(f16x8, au), __builtin_bit_cast(f16x8, bu),
          acc, 0, 0, 0);
    }
    const int o0 = ot * 16 + g * 4;
    const float4 b4 = *(const float4*)(bi + o0);
    const h2 p0 = {(_Float16)(acc[0] + b4.x), (_Float16)(acc[1] + b4.y)};
    const h2 p1 = {(_Float16)(acc[2] + b4.z), (_Float16)(acc[3] + b4.w)};
    const int col = bt * 16 + r;
    h1pk[(size_t)(ot * 8 + g * 2) * BB + col]     = h2u(p0);
    h1pk[(size_t)(ot * 8 + g * 2 + 1) * BB + col] = h2u(p1);
  }
  grid.sync();

  // ========== phase 2: max-plus ==========
  // units u = 2*bid, 2*bid+1 share og = bid>>1; bg0 = (bid&1)*2.
  mmplus_og<true>(h1pk, Wmax, h2pk, wtile, red, bid >> 1, (bid & 1) * 2);
  grid.sync();

  // ========== phase 3: min-plus ==========
  mmplus_og<false>(h2pk, Wmin, h3pk, wtile, red, bid >> 1, (bid & 1) * 2);
  grid.sync();

  // ========== phase 4: fc_out (blocks 0..71: a = bid>>2, bg = bid&3) ======
  if (bid < AA * 4) {
    const int a  = bid >> 2;
    const int bg = bid & 3;
    const int bl = t & 63;
    const int ks = __builtin_amdgcn_readfirstlane(t >> 6);  // 0..15
    float* fred = (float*)red;

    const unsigned int* hp = h3pk + (size_t)(ks * 32) * BB + bg * 64 + bl;
    const float* w = Wo + (size_t)a * HH + ks * 64;

    float acc = 0.f;
#pragma unroll 8
    for (int d = 0; d < 32; ++d) {
      const h2 hv = u2h(hp[(size_t)d * BB]);
      acc = fmaf((float)hv.x, w[2 * d], acc);
      acc = fmaf((float)hv.y, w[2 * d + 1], acc);
    }
    fred[ks * 64 + bl] = acc;
    __syncthreads();

    if (t < 64) {
      float m = bo[a];
#pragma unroll
      for (int ks2 = 0; ks2 < 16; ++ks2) m += fred[ks2 * 64 + t];
      q[(size_t)(bg * 64 + t) * AA + a] = m;
    }
  }
}

// ---------------------------------------------------------------------------
extern "C" void kernel_launch(void* const* d_in, const int* in_sizes, int n_in,
                              void* d_out, int out_size, void* d_ws, size_t ws_size,
                              hipStream_t stream) {
  const float* x    = (const float*)d_in[0];
  const float* Wi   = (const float*)d_in[1];
  const float* bi   = (const float*)d_in[2];
  const float* Wmax = (const float*)d_in[3];
  const float* Wmin = (const float*)d_in[4];
  const float* Wo   = (const float*)d_in[5];
  const float* bo   = (const float*)d_in[6];
  float* q = (float*)d_out;

  char* ws = (char*)d_ws;
  unsigned int* h1pk = (unsigned int*)ws;  ws += (size_t)(HH / 2) * BB * 4;  // 512 KB
  unsigned int* h2pk = (unsigned int*)ws;  ws += (size_t)(HH / 2) * BB * 4;
  unsigned int* h3pk = (unsigned int*)ws;

  void* args[] = {(void*)&x,    (void*)&Wi,   (void*)&bi,  (void*)&Wmax,
                  (void*)&Wmin, (void*)&Wo,   (void*)&bo,  (void*)&q,
                  (void*)&h1pk, (void*)&h2pk, (void*)&h3pk};
  hipLaunchCooperativeKernel((const void*)fused_kernel, dim3(256), dim3(1024),
                             args, 0, stream);
}

// Round 4
// 104.915 us; speedup vs baseline: 1.8305x; 1.8305x over previous
//
#include <hip/hip_runtime.h>
#include <math.h>

#define BB   256   // batch
#define OBS  256
#define HH   1024
#define AA   18

// clang-native packed f16: + -> v_pk_add_f16, elementwise_max -> v_pk_max_f16
typedef _Float16 h2 __attribute__((ext_vector_type(2)));
typedef _Float16 f16x8 __attribute__((ext_vector_type(8)));
typedef float f32x4 __attribute__((ext_vector_type(4)));

static __device__ __forceinline__ h2 u2h(unsigned int u) {
  return __builtin_bit_cast(h2, u);
}
static __device__ __forceinline__ unsigned int h2u(h2 v) {
  return __builtin_bit_cast(unsigned int, v);
}
// v_cvt_pkrtz_f16_f32: two f32 -> packed f16 dword (builtin returns __fp16x2)
static __device__ __forceinline__ unsigned int pkrtz(float a, float b) {
  return __builtin_bit_cast(unsigned int, __builtin_amdgcn_cvt_pkrtz(a, b));
}

// ---------------------------------------------------------------------------
// fc_in (MFMA): h1pk[o/2][b] = pack_f16( x@W_in^T + b_in )
// One wave computes a 16o x 16b tile over K=256 via 8x mfma_f32_16x16x32_f16.
// No LDS, no barriers (R2-verified correct & neutral-to-better).
// ---------------------------------------------------------------------------
__global__ __launch_bounds__(256) void fc_in_kernel(
    const float* __restrict__ x, const float* __restrict__ Wi,
    const float* __restrict__ bi, unsigned int* __restrict__ h1pk) {
  const int t    = threadIdx.x;
  const int lane = t & 63;
  const int wid  = blockIdx.x * 4 + (t >> 6);   // 0..1023
  const int ot   = wid >> 4;                    // 0..63  (16 o rows)
  const int bt   = wid & 15;                    // 0..15  (16 b cols)
  const int r    = lane & 15;
  const int g    = lane >> 4;                   // 0..3

  const float* __restrict__ wrow = Wi + (size_t)(ot * 16 + r) * OBS + g * 8;
  const float* __restrict__ xrow = x  + (size_t)(bt * 16 + r) * OBS + g * 8;

  f32x4 acc = {0.f, 0.f, 0.f, 0.f};
#pragma unroll
  for (int ks = 0; ks < 8; ++ks) {
    const float4 wa = *(const float4*)(wrow + ks * 32);
    const float4 wb = *(const float4*)(wrow + ks * 32 + 4);
    const float4 xa = *(const float4*)(xrow + ks * 32);
    const float4 xb = *(const float4*)(xrow + ks * 32 + 4);
    const uint4 au = make_uint4(pkrtz(wa.x, wa.y), pkrtz(wa.z, wa.w),
                                pkrtz(wb.x, wb.y), pkrtz(wb.z, wb.w));
    const uint4 bu = make_uint4(pkrtz(xa.x, xa.y), pkrtz(xa.z, xa.w),
                                pkrtz(xb.x, xb.y), pkrtz(xb.z, xb.w));
    acc = __builtin_amdgcn_mfma_f32_16x16x32_f16(
        __builtin_bit_cast(f16x8, au), __builtin_bit_cast(f16x8, bu),
        acc, 0, 0, 0);
  }

  const int o0 = ot * 16 + g * 4;
  const float4 b4 = *(const float4*)(bi + o0);
  const h2 p0 = {(_Float16)(acc[0] + b4.x), (_Float16)(acc[1] + b4.y)};
  const h2 p1 = {(_Float16)(acc[2] + b4.z), (_Float16)(acc[3] + b4.w)};
  const int col = bt * 16 + r;
  h1pk[(size_t)(ot * 8 + g * 2) * BB + col]     = h2u(p0);
  h1pk[(size_t)(ot * 8 + g * 2 + 1) * BB + col] = h2u(p1);
}

// ---------------------------------------------------------------------------
// mmplus v3 (deep software pipeline): out[o][b] = OP_i( W[o][i] + h[i][b] )
// grid (H/8, B/64) = 512 blocks, block 1024 = 16 i-splits (64 i each).
// Main loop restructured as 8 chunks x 2 iterations with issue-early /
// consume-late register double-buffering of BOTH the h global loads (4x
// uint4/chunk) and the W LDS reads (4x uint2/chunk). Theory (R3 counters:
// VALUBusy 14%, HBM 1.8%, stalls ~85%): depth-1 prefetch left ~1800cy of
// exposed L2/L3 + LDS latency per iteration; this gives each wave 4
// outstanding vmem + 4 outstanding ds ops, removing loads from the critical
// chain. All buffer indices compile-time (rule #20).
// ---------------------------------------------------------------------------
template <bool IS_MAX>
static __device__ __forceinline__ void mm_iter(h2 (&acc)[2][4],
                                               const uint4& he, const uint4& ho,
                                               const uint2& w0, const uint2& w1) {
  const h2 h0v[4] = {u2h(he.x), u2h(he.y), u2h(he.z), u2h(he.w)};
  const h2 h1v[4] = {u2h(ho.x), u2h(ho.y), u2h(ho.z), u2h(ho.w)};
  const h2 wa[2] = {u2h(w0.x), u2h(w1.x)};
  const h2 wb[2] = {u2h(w0.y), u2h(w1.y)};
#pragma unroll
  for (int j = 0; j < 2; ++j) {
#pragma unroll
    for (int bb = 0; bb < 4; ++bb) {
      if (IS_MAX) {
        acc[j][bb] = __builtin_elementwise_max(acc[j][bb], wa[j] + h0v[bb]);
        acc[j][bb] = __builtin_elementwise_max(acc[j][bb], wb[j] + h1v[bb]);
      } else {
        acc[j][bb] = __builtin_elementwise_min(acc[j][bb], wa[j] + h0v[bb]);
        acc[j][bb] = __builtin_elementwise_min(acc[j][bb], wb[j] + h1v[bb]);
      }
    }
  }
}

template <bool IS_MAX>
__global__ __launch_bounds__(1024) void mmplus_kernel(
    const unsigned int* __restrict__ hpk,   // [H/2][B] dwords (i-pair, b)
    const float* __restrict__ Wf,           // [H][H] f32 (o, i)
    unsigned int* __restrict__ opk) {       // [H/2][B]
  constexpr int PITCH = 514;
  __shared__ __align__(16) unsigned int lds[8 * PITCH];  // 16.4 KB; red aliases
  const int t    = threadIdx.x;
  const int lane = t & 63;
  const int og2  = lane >> 4;      // o-pair group 0..3
  const int bq   = lane & 15;      // b-quad 0..15
  const int s    = __builtin_amdgcn_readfirstlane(t >> 6);  // i-split 0..15
  const int og   = blockIdx.x;     // 0..127, 8 o each
  const int bg   = blockIdx.y;

  // ---- stage W tile: 8 rows (two waves per row), f32 -> pk f16 ----
  {
    const int o_l = t >> 7;        // 0..7
    const int c   = t & 127;
    const float4* src = (const float4*)(Wf + (size_t)(og * 8 + o_l) * HH);
    unsigned int* dst = &lds[o_l * PITCH];
#pragma unroll
    for (int k = 0; k < 2; ++k) {
      const float4 v = src[c + 128 * k];
      *(uint2*)&dst[(c + 128 * k) * 2] =
          make_uint2(pkrtz(v.x, v.y), pkrtz(v.z, v.w));
    }
  }
  __syncthreads();

  const unsigned int* __restrict__ hp =
      hpk + (size_t)(s * 32) * BB + bg * 64 + bq * 4;
  const unsigned int* __restrict__ wl = &lds[(og2 * 2) * PITCH + s * 32];

  const _Float16 INIT = (_Float16)(IS_MAX ? -65504.f : 65504.f);
  h2 acc[2][4];
#pragma unroll
  for (int j = 0; j < 2; ++j)
#pragma unroll
    for (int bb = 0; bb < 4; ++bb) acc[j][bb] = (h2){INIT, INIT};

#define LDH(p) (*(const uint4*)(hp + (size_t)(p) * BB))
#define LDW(j, p) (*(const uint2*)(wl + (j) * PITCH + (p)))

  // prologue: chunk 0 (iterations 0,1 -> i-pair rows 0..3)
  uint4 hA0 = LDH(0), hA1 = LDH(1), hA2 = LDH(2), hA3 = LDH(3);
  uint2 wA00 = LDW(0, 0), wA01 = LDW(0, 2);
  uint2 wA10 = LDW(1, 0), wA11 = LDW(1, 2);

#pragma unroll
  for (int c = 0; c < 8; ++c) {
    uint4 hB0, hB1, hB2, hB3;
    uint2 wB00, wB01, wB10, wB11;
    if (c < 7) {                       // compile-time after full unroll
      const int p = 4 * (c + 1);
      hB0 = LDH(p);     hB1 = LDH(p + 1);
      hB2 = LDH(p + 2); hB3 = LDH(p + 3);
      wB00 = LDW(0, p); wB01 = LDW(0, p + 2);
      wB10 = LDW(1, p); wB11 = LDW(1, p + 2);
    }
    // iteration 2c   : rows 4c, 4c+1
    mm_iter<IS_MAX>(acc, hA0, hA1, wA00, wA10);
    // iteration 2c+1 : rows 4c+2, 4c+3
    mm_iter<IS_MAX>(acc, hA2, hA3, wA01, wA11);
    if (c < 7) {
      hA0 = hB0; hA1 = hB1; hA2 = hB2; hA3 = hB3;
      wA00 = wB00; wA01 = wB01; wA10 = wB10; wA11 = wB11;
    }
  }
#undef LDH
#undef LDW

  // fold even/odd i-partials -> scalar f16 per (o,b); pack this thread's
  // o-pair (j=0 even row, j=1 odd row)
  unsigned int opack[4];
#pragma unroll
  for (int bb = 0; bb < 4; ++bb) {
    const h2 ae = acc[0][bb], ao = acc[1][bb];
    const _Float16 me = IS_MAX ? (ae.x > ae.y ? ae.x : ae.y)
                               : (ae.x < ae.y ? ae.x : ae.y);
    const _Float16 mo = IS_MAX ? (ao.x > ao.y ? ao.x : ao.y)
                               : (ao.x < ao.y ? ao.x : ao.y);
    opack[bb] = h2u((h2){me, mo});
  }

  __syncthreads();  // W reads done; reuse lds[] as red[16][4][64] (16 KB)
#pragma unroll
  for (int bb = 0; bb < 4; ++bb)
    lds[s * 256 + og2 * 64 + bq * 4 + bb] = opack[bb];
  __syncthreads();

  if (t < 256) {
    const int op = t >> 6;   // o-pair 0..3
    const int bl = t & 63;
    h2 m = u2h(lds[op * 64 + bl]);
#pragma unroll
    for (int ks = 1; ks < 16; ++ks) {
      const h2 v = u2h(lds[ks * 256 + op * 64 + bl]);
      m = IS_MAX ? __builtin_elementwise_max(m, v)
                 : __builtin_elementwise_min(m, v);
    }
    opk[(size_t)(og * 4 + op) * BB + bg * 64 + bl] = h2u(m);
  }
}

// ---------------------------------------------------------------------------
// fc_out: q[b][a] = bo[a] + dot(h3[:,b], W_out[a,:])
// grid (A, B/64), block 1024 = 16 k-splits x 64 b.
// ---------------------------------------------------------------------------
__global__ __launch_bounds__(1024) void fc_out_kernel(
    const unsigned int* __restrict__ h3pk, const float* __restrict__ Wo,
    const float* __restrict__ bo, float* __restrict__ q) {
  __shared__ float red[16][64];
  const int a  = blockIdx.x;
  const int bg = blockIdx.y;
  const int t  = threadIdx.x;
  const int bl = t & 63;
  const int ks = __builtin_amdgcn_readfirstlane(t >> 6);  // 0..15

  const unsigned int* __restrict__ hp =
      h3pk + (size_t)(ks * 32) * BB + bg * 64 + bl;
  const float* __restrict__ w = Wo + (size_t)a * HH + ks * 64;

  float acc = 0.f;
#pragma unroll 8
  for (int d = 0; d < 32; ++d) {
    const h2 hv = u2h(hp[(size_t)d * BB]);
    acc = fmaf((float)hv.x, w[2 * d], acc);
    acc = fmaf((float)hv.y, w[2 * d + 1], acc);
  }
  red[ks][bl] = acc;
  __syncthreads();

  if (t < 64) {
    float m = bo[a];
#pragma unroll
    for (int ks2 = 0; ks2 < 16; ++ks2) m += red[ks2][t];
    q[(size_t)(bg * 64 + t) * AA + a] = m;
  }
}

// ---------------------------------------------------------------------------
extern "C" void kernel_launch(void* const* d_in, const int* in_sizes, int n_in,
                              void* d_out, int out_size, void* d_ws, size_t ws_size,
                              hipStream_t stream) {
  const float* x    = (const float*)d_in[0];
  const float* Wi   = (const float*)d_in[1];
  const float* bi   = (const float*)d_in[2];
  const float* Wmax = (const float*)d_in[3];
  const float* Wmin = (const float*)d_in[4];
  const float* Wo   = (const float*)d_in[5];
  const float* bo   = (const float*)d_in[6];
  float* q = (float*)d_out;

  char* ws = (char*)d_ws;
  unsigned int* h1pk = (unsigned int*)ws;  ws += (size_t)(HH / 2) * BB * 4;  // 512 KB
  unsigned int* h2pk = (unsigned int*)ws;  ws += (size_t)(HH / 2) * BB * 4;
  unsigned int* h3pk = (unsigned int*)ws;

  fc_in_kernel<<<dim3(256), 256, 0, stream>>>(x, Wi, bi, h1pk);
  mmplus_kernel<true ><<<dim3(HH / 8, BB / 64), 1024, 0, stream>>>(h1pk, Wmax, h2pk);
  mmplus_kernel<false><<<dim3(HH / 8, BB / 64), 1024, 0, stream>>>(h2pk, Wmin, h3pk);
  fc_out_kernel<<<dim3(AA, BB / 64), 1024, 0, stream>>>(h3pk, Wo, bo, q);
}